// Round 5
// baseline (191.832 us; speedup 1.0000x reference)
//
#include <hip/hip_runtime.h>
#include <stdint.h>

#define N_Q    4096
#define D_K    512
#define D_OUT  16384
#define NCLUST 256

// GEMM geometry: 128x256 tile, BK=32, 8 waves (2M x 4N), per-wave 64x64 output.
// Ring-3 LDS (72 KB) -> 2 WGs/CU co-resident (the round-5 lever: inter-WG overlap
// of LDS-phase / MFMA-phase / epilogue-drain). Counted vmcnt, swizzled LDS (T2),
// setprio (T5), XCD N-partition (T1).
#define BM 128
#define BN 256
#define BK 32
#define NT (D_K / BK)   // 16 K-tiles

typedef __attribute__((ext_vector_type(4))) float f32x4;
typedef __attribute__((ext_vector_type(8))) short bf16x8;

// round-to-nearest-even f32 -> bf16
__device__ __forceinline__ uint32_t f2bf(float f) {
  uint32_t u = __float_as_uint(f);
  u += 0x7FFFu + ((u >> 16) & 1u);
  return u >> 16;
}

#define GLOAD_LDS16(g, l)                                         \
  __builtin_amdgcn_global_load_lds(                               \
      (const __attribute__((address_space(1))) void*)(g),         \
      (__attribute__((address_space(3))) void*)(l), 16, 0, 0)

// counted-vmcnt wait fused with barrier (loop top); memory clobber pins mem ops
#define WAIT_BAR(N) asm volatile("s_waitcnt vmcnt(" #N ")\n\ts_barrier" ::: "memory")

__global__ __launch_bounds__(256) void cvt_bf16_kernel(const float* __restrict__ src,
                                                       ushort* __restrict__ dst, int n8) {
  int i = blockIdx.x * 256 + threadIdx.x;
  if (i >= n8) return;
  const float4* s = reinterpret_cast<const float4*>(src) + (size_t)i * 2;
  float4 v0 = s[0], v1 = s[1];
  uint4 o;
  o.x = f2bf(v0.x) | (f2bf(v0.y) << 16);
  o.y = f2bf(v0.z) | (f2bf(v0.w) << 16);
  o.z = f2bf(v1.x) | (f2bf(v1.y) << 16);
  o.w = f2bf(v1.z) | (f2bf(v1.w) << 16);
  reinterpret_cast<uint4*>(dst)[i] = o;
}

// centT4[k4][c] transpose for coalesced routing loads; also zeroes cmask (block 0)
__global__ __launch_bounds__(256) void transpose_cent_kernel(const float* __restrict__ cent,
                                                             float4* __restrict__ centT4,
                                                             float* __restrict__ cmask) {
  if (blockIdx.x == 0) cmask[threadIdx.x] = 0.0f;
  int idx = blockIdx.x * 256 + threadIdx.x;
  int k4 = idx & 127, c = idx >> 7;
  float4 v = *reinterpret_cast<const float4*>(&cent[(size_t)c * D_K + k4 * 4]);
  centT4[(size_t)k4 * NCLUST + c] = v;
}

// 8 queries/block; thread t owns centroid t; fused A f32->bf16 convert.
// f32 routing math throughout (threshold booleans must not flip).
__global__ __launch_bounds__(256) void routing_kernel(const float* __restrict__ input,
                                                      const float4* __restrict__ centT4,
                                                      float* __restrict__ qmask,
                                                      float* __restrict__ cmask,
                                                      ushort* __restrict__ A_bf) {
  __shared__ float lgs[8][NCLUST];
  int c = threadIdx.x;
  int q0 = blockIdx.x * 8;
  const float* __restrict__ inp = input + (size_t)q0 * D_K;

  {
    const float4* s4 = reinterpret_cast<const float4*>(inp) + c * 4;
    float4 x0 = s4[0], x1 = s4[1], x2 = s4[2], x3 = s4[3];
    uint4 o0, o1;
    o0.x = f2bf(x0.x) | (f2bf(x0.y) << 16);
    o0.y = f2bf(x0.z) | (f2bf(x0.w) << 16);
    o0.z = f2bf(x1.x) | (f2bf(x1.y) << 16);
    o0.w = f2bf(x1.z) | (f2bf(x1.w) << 16);
    o1.x = f2bf(x2.x) | (f2bf(x2.y) << 16);
    o1.y = f2bf(x2.z) | (f2bf(x2.w) << 16);
    o1.z = f2bf(x3.x) | (f2bf(x3.y) << 16);
    o1.w = f2bf(x3.z) | (f2bf(x3.w) << 16);
    uint4* dst = reinterpret_cast<uint4*>(A_bf + (size_t)q0 * D_K);
    dst[c * 2] = o0;
    dst[c * 2 + 1] = o1;
  }

  float acc[8] = {0, 0, 0, 0, 0, 0, 0, 0};
  for (int k4 = 0; k4 < D_K / 4; ++k4) {
    float4 v = centT4[(size_t)k4 * NCLUST + c];
#pragma unroll
    for (int q = 0; q < 8; ++q) {
      float4 r = *reinterpret_cast<const float4*>(&inp[q * D_K + k4 * 4]);  // uniform addr
      acc[q] += v.x * r.x + v.y * r.y + v.z * r.z + v.w * r.w;
    }
  }
#pragma unroll
  for (int q = 0; q < 8; ++q) lgs[q][c] = acc[q] * 10.0f;  // /TEMPERATURE
  __syncthreads();

  int wave = c >> 6, lane = c & 63;
#pragma unroll
  for (int qq = 0; qq < 2; ++qq) {
    int q = wave * 2 + qq;
    float4 lv = *reinterpret_cast<const float4*>(&lgs[q][lane * 4]);
    float m = fmaxf(fmaxf(lv.x, lv.y), fmaxf(lv.z, lv.w));
#pragma unroll
    for (int off = 32; off > 0; off >>= 1) m = fmaxf(m, __shfl_xor(m, off));
    float e0 = expf(lv.x - m), e1 = expf(lv.y - m), e2 = expf(lv.z - m), e3 = expf(lv.w - m);
    float s = e0 + e1 + e2 + e3;
#pragma unroll
    for (int off = 32; off > 0; off >>= 1) s += __shfl_xor(s, off);
    float thr = 0.01f * s;
    bool a0 = e0 > thr, a1 = e1 > thr, a2 = e2 > thr, a3 = e3 > thr;
    if (a0) cmask[lane * 4 + 0] = 1.0f;  // benign races: all writers store 1.0
    if (a1) cmask[lane * 4 + 1] = 1.0f;
    if (a2) cmask[lane * 4 + 2] = 1.0f;
    if (a3) cmask[lane * 4 + 3] = 1.0f;
    unsigned long long any = __ballot(a0 | a1 | a2 | a3);
    if (lane == 0) qmask[q0 + q] = any ? 1.0f : 0.0f;
  }
}

__global__ __launch_bounds__(512, 4) void gemm_masked_kernel(
    const ushort* __restrict__ A, const ushort* __restrict__ W,
    const float* __restrict__ bias, const int* __restrict__ assign,
    const float* __restrict__ qmask, const float* __restrict__ cmask,
    float* __restrict__ C) {
  __shared__ ushort sA[3][BM * BK];  // 3 x 8 KiB
  __shared__ ushort sB[3][BN * BK];  // 3 x 16 KiB  -> 72 KiB total -> 2 WG/CU

  int tid = threadIdx.x;
  int wave = tid >> 6, lane = tid & 63;

  // XCD N-partition: XCD x owns ntiles [8x, 8x+8); within an XCD walk mtiles
  // for a fixed ntile (W-panel 2 MB stays L2-hot; A is 4 MB -> L3-resident).
  // 2048 % 8 == 0 -> bijective.
  int bid = blockIdx.x;
  int r2 = bid >> 3;                            // 0..255
  int ntile = (bid & 7) * 8 + (r2 >> 5);        // 0..63
  int mtile = r2 & 31;                          // 0..31
  int m0 = mtile * BM, n0 = ntile * BN;

  int wr = wave >> 2, wc = wave & 3;  // 2x4 wave grid; per-wave C: 64x64

  const ushort* gA = A + (size_t)m0 * D_K;
  const ushort* gB = W + (size_t)n0 * D_K;

  // staging: LDS slot (row, kg) <- global (row, kg ^ ((row>>1)&3)); linear LDS dest,
  // pre-swizzled per-lane global source (rule #21). ((128+row)>>1)&3 == ((row>>1)&3).
  int srow = tid >> 2;        // 0..127
  int kg = tid & 3;
  int ks = (kg ^ ((srow >> 1) & 3)) * 8;
  const ushort* srcA0 = gA + (size_t)srow * D_K + ks;                  // A rows 0..127
  const ushort* srcB0 = gB + (size_t)srow * D_K + ks;                  // B rows 0..127
  const ushort* srcB1 = gB + (size_t)(128 + srow) * D_K + ks;          // B rows 128..255
  int ldso = wave * 512;  // wave's 1KB chunk (16 rows) within an 8 KB half-region

#define STAGE(buf, kt) do {                              \
    GLOAD_LDS16(srcA0 + (kt), &sA[buf][ldso]);           \
    GLOAD_LDS16(srcB0 + (kt), &sB[buf][ldso]);           \
    GLOAD_LDS16(srcB1 + (kt), &sB[buf][4096 + ldso]);    \
  } while (0)

  // fragment read indices (swizzled): elem (r, kg0*8..+8) at r*32 + (kg0^((r>>1)&3))*8
  int kg0 = lane >> 4, l15 = lane & 15;
  int aIdx[4], bIdx[4];
#pragma unroll
  for (int m = 0; m < 4; ++m) {
    int r = wr * 64 + m * 16 + l15;
    aIdx[m] = r * 32 + ((kg0 ^ ((r >> 1) & 3)) << 3);
  }
#pragma unroll
  for (int n = 0; n < 4; ++n) {
    int r = wc * 64 + n * 16 + l15;
    bIdx[n] = r * 32 + ((kg0 ^ ((r >> 1) & 3)) << 3);
  }

  f32x4 acc[4][4] = {};

  STAGE(0, 0);
  STAGE(1, BK);

#pragma unroll
  for (int t = 0; t < NT; ++t) {
    // loop top: tile t's 3 loads are the wave's oldest; tile t+1's 3 stay in flight.
    if (t < NT - 1) { WAIT_BAR(3); } else { WAIT_BAR(0); }

    const ushort* sa = sA[t % 3];
    const ushort* sb = sB[t % 3];
    bf16x8 af[4], bf[4];
#pragma unroll
    for (int n = 0; n < 4; ++n) bf[n] = *reinterpret_cast<const bf16x8*>(&sb[bIdx[n]]);
#pragma unroll
    for (int m = 0; m < 4; ++m) af[m] = *reinterpret_cast<const bf16x8*>(&sa[aIdx[m]]);
    if (t + 2 < NT) STAGE((t + 2) % 3, (t + 2) * BK);  // buf (t+2)%3==(t-1)%3: reads retired

    __builtin_amdgcn_s_setprio(1);
#pragma unroll
    for (int m = 0; m < 4; ++m)
#pragma unroll
      for (int n = 0; n < 4; ++n)
        acc[m][n] = __builtin_amdgcn_mfma_f32_16x16x32_bf16(af[m], bf[n], acc[m][n], 0, 0, 0);
    __builtin_amdgcn_s_setprio(0);
    // closing barrier is next iteration's WAIT_BAR (or loop exit)
  }
#undef STAGE

  // epilogue: C/D layout col=lane&15, row=(lane>>4)*4+reg. m-outer to cap VGPR.
  // Nontemporal: C is write-once (268 MB) — keep W/A panels resident in L2.
  int lr = lane >> 4;
  float bj[4], rm[4];
#pragma unroll
  for (int n = 0; n < 4; ++n) {
    int col = n0 + wc * 64 + n * 16 + l15;
    bj[n] = bias[col];
    rm[n] = cmask[assign[col]];
  }
#pragma unroll
  for (int m = 0; m < 4; ++m) {
    size_t rbase = (size_t)(m0 + wr * 64 + m * 16 + lr * 4);
    float4 qm = *reinterpret_cast<const float4*>(&qmask[rbase]);
#pragma unroll
    for (int n = 0; n < 4; ++n) {
      int col = n0 + wc * 64 + n * 16 + l15;
      __builtin_nontemporal_store((acc[m][n][0] + bj[n]) * qm.x * rm[n], &C[(rbase + 0) * D_OUT + col]);
      __builtin_nontemporal_store((acc[m][n][1] + bj[n]) * qm.y * rm[n], &C[(rbase + 1) * D_OUT + col]);
      __builtin_nontemporal_store((acc[m][n][2] + bj[n]) * qm.z * rm[n], &C[(rbase + 2) * D_OUT + col]);
      __builtin_nontemporal_store((acc[m][n][3] + bj[n]) * qm.w * rm[n], &C[(rbase + 3) * D_OUT + col]);
    }
  }
}

extern "C" void kernel_launch(void* const* d_in, const int* in_sizes, int n_in,
                              void* d_out, int out_size, void* d_ws, size_t ws_size,
                              hipStream_t stream) {
  const float* input     = (const float*)d_in[0];
  const float* weight    = (const float*)d_in[1];
  const float* bias      = (const float*)d_in[2];
  const float* centroids = (const float*)d_in[3];
  const int*   assign    = (const int*)d_in[4];
  float* out = (float*)d_out;

  // ws layout (bytes):
  //   A_bf16 : 0          (4 MiB)
  //   W_bf16 : 4,194,304  (16 MiB)
  //   qmask  : 20,971,520 (16 KB)
  //   cmask  : 20,987,904 (1 KB)
  //   centT4 : 21,000,192 (512 KB)
  char* ws = (char*)d_ws;
  ushort* A_bf   = (ushort*)ws;
  ushort* W_bf   = (ushort*)(ws + 4194304);
  float*  qmask  = (float*)(ws + 20971520);
  float*  cmask  = (float*)(ws + 20987904);
  float4* centT4 = (float4*)(ws + 21000192);

  cvt_bf16_kernel<<<(D_OUT * D_K / 8 + 255) / 256, 256, 0, stream>>>(weight, W_bf, D_OUT * D_K / 8);
  transpose_cent_kernel<<<128, 256, 0, stream>>>(centroids, centT4, cmask);
  routing_kernel<<<N_Q / 8, 256, 0, stream>>>(input, centT4, qmask, cmask, A_bf);
  gemm_masked_kernel<<<(N_Q / BM) * (D_OUT / BN), 512, 0, stream>>>(
      A_bf, W_bf, bias, assign, qmask, cmask, out);
}

// Round 6
// 151.270 us; speedup vs baseline: 1.2681x; 1.2681x over previous
//
#include <hip/hip_runtime.h>
#include <stdint.h>

#define N_Q    4096
#define D_K    512
#define D_OUT  16384
#define NCLUST 256

// GEMM geometry: 128x256 tile, BK=32, 8 waves (2M x 4N), per-wave 64x64 output.
// Ring-3 LDS (72 KB) -> 2 WGs/CU. Counted vmcnt, swizzled LDS (T2), setprio (T5),
// XCD N-partition (T1). Round-6 lever: LDS-transposed epilogue -> full-line
// (1 KB contiguous per wave-instr) nontemporal C stores, killing the L2
// write-allocate fills (126 MB bogus FETCH) that made rounds 2-5 write-bound.
#define BM 128
#define BN 256
#define BK 32
#define NT (D_K / BK)   // 16 K-tiles
#define SCP 264         // epilogue sC row stride (floats): 2-way bank pattern

typedef __attribute__((ext_vector_type(4))) float f32x4;
typedef __attribute__((ext_vector_type(8))) short bf16x8;

// round-to-nearest-even f32 -> bf16
__device__ __forceinline__ uint32_t f2bf(float f) {
  uint32_t u = __float_as_uint(f);
  u += 0x7FFFu + ((u >> 16) & 1u);
  return u >> 16;
}

#define GLOAD_LDS16(g, l)                                         \
  __builtin_amdgcn_global_load_lds(                               \
      (const __attribute__((address_space(1))) void*)(g),         \
      (__attribute__((address_space(3))) void*)(l), 16, 0, 0)

// counted-vmcnt wait fused with barrier (loop top); memory clobber pins mem ops
#define WAIT_BAR(N) asm volatile("s_waitcnt vmcnt(" #N ")\n\ts_barrier" ::: "memory")

__global__ __launch_bounds__(256) void cvt_bf16_kernel(const float* __restrict__ src,
                                                       ushort* __restrict__ dst, int n8) {
  int i = blockIdx.x * 256 + threadIdx.x;
  if (i >= n8) return;
  const float4* s = reinterpret_cast<const float4*>(src) + (size_t)i * 2;
  float4 v0 = s[0], v1 = s[1];
  uint4 o;
  o.x = f2bf(v0.x) | (f2bf(v0.y) << 16);
  o.y = f2bf(v0.z) | (f2bf(v0.w) << 16);
  o.z = f2bf(v1.x) | (f2bf(v1.y) << 16);
  o.w = f2bf(v1.z) | (f2bf(v1.w) << 16);
  reinterpret_cast<uint4*>(dst)[i] = o;
}

// centT4[k4][c] transpose for coalesced routing loads; also zeroes cmask (block 0)
__global__ __launch_bounds__(256) void transpose_cent_kernel(const float* __restrict__ cent,
                                                             float4* __restrict__ centT4,
                                                             float* __restrict__ cmask) {
  if (blockIdx.x == 0) cmask[threadIdx.x] = 0.0f;
  int idx = blockIdx.x * 256 + threadIdx.x;
  int k4 = idx & 127, c = idx >> 7;
  float4 v = *reinterpret_cast<const float4*>(&cent[(size_t)c * D_K + k4 * 4]);
  centT4[(size_t)k4 * NCLUST + c] = v;
}

// 8 queries/block; thread t owns centroid t; fused A f32->bf16 convert.
// f32 routing math throughout (threshold booleans must not flip).
__global__ __launch_bounds__(256) void routing_kernel(const float* __restrict__ input,
                                                      const float4* __restrict__ centT4,
                                                      float* __restrict__ qmask,
                                                      float* __restrict__ cmask,
                                                      ushort* __restrict__ A_bf) {
  __shared__ float lgs[8][NCLUST];
  int c = threadIdx.x;
  int q0 = blockIdx.x * 8;
  const float* __restrict__ inp = input + (size_t)q0 * D_K;

  {
    const float4* s4 = reinterpret_cast<const float4*>(inp) + c * 4;
    float4 x0 = s4[0], x1 = s4[1], x2 = s4[2], x3 = s4[3];
    uint4 o0, o1;
    o0.x = f2bf(x0.x) | (f2bf(x0.y) << 16);
    o0.y = f2bf(x0.z) | (f2bf(x0.w) << 16);
    o0.z = f2bf(x1.x) | (f2bf(x1.y) << 16);
    o0.w = f2bf(x1.z) | (f2bf(x1.w) << 16);
    o1.x = f2bf(x2.x) | (f2bf(x2.y) << 16);
    o1.y = f2bf(x2.z) | (f2bf(x2.w) << 16);
    o1.z = f2bf(x3.x) | (f2bf(x3.y) << 16);
    o1.w = f2bf(x3.z) | (f2bf(x3.w) << 16);
    uint4* dst = reinterpret_cast<uint4*>(A_bf + (size_t)q0 * D_K);
    dst[c * 2] = o0;
    dst[c * 2 + 1] = o1;
  }

  float acc[8] = {0, 0, 0, 0, 0, 0, 0, 0};
  for (int k4 = 0; k4 < D_K / 4; ++k4) {
    float4 v = centT4[(size_t)k4 * NCLUST + c];
#pragma unroll
    for (int q = 0; q < 8; ++q) {
      float4 r = *reinterpret_cast<const float4*>(&inp[q * D_K + k4 * 4]);  // uniform addr
      acc[q] += v.x * r.x + v.y * r.y + v.z * r.z + v.w * r.w;
    }
  }
#pragma unroll
  for (int q = 0; q < 8; ++q) lgs[q][c] = acc[q] * 10.0f;  // /TEMPERATURE
  __syncthreads();

  int wave = c >> 6, lane = c & 63;
#pragma unroll
  for (int qq = 0; qq < 2; ++qq) {
    int q = wave * 2 + qq;
    float4 lv = *reinterpret_cast<const float4*>(&lgs[q][lane * 4]);
    float m = fmaxf(fmaxf(lv.x, lv.y), fmaxf(lv.z, lv.w));
#pragma unroll
    for (int off = 32; off > 0; off >>= 1) m = fmaxf(m, __shfl_xor(m, off));
    float e0 = expf(lv.x - m), e1 = expf(lv.y - m), e2 = expf(lv.z - m), e3 = expf(lv.w - m);
    float s = e0 + e1 + e2 + e3;
#pragma unroll
    for (int off = 32; off > 0; off >>= 1) s += __shfl_xor(s, off);
    float thr = 0.01f * s;
    bool a0 = e0 > thr, a1 = e1 > thr, a2 = e2 > thr, a3 = e3 > thr;
    if (a0) cmask[lane * 4 + 0] = 1.0f;  // benign races: all writers store 1.0
    if (a1) cmask[lane * 4 + 1] = 1.0f;
    if (a2) cmask[lane * 4 + 2] = 1.0f;
    if (a3) cmask[lane * 4 + 3] = 1.0f;
    unsigned long long any = __ballot(a0 | a1 | a2 | a3);
    if (lane == 0) qmask[q0 + q] = any ? 1.0f : 0.0f;
  }
}

__global__ __launch_bounds__(512, 4) void gemm_masked_kernel(
    const ushort* __restrict__ A, const ushort* __restrict__ W,
    const float* __restrict__ bias, const int* __restrict__ assign,
    const float* __restrict__ qmask, const float* __restrict__ cmask,
    float* __restrict__ C) {
  // single 72 KB block: K-loop uses sA(24K)+sB(48K); epilogue reuses the front
  // 33.8 KB as sC (after a barrier). 72 KB -> 2 WG/CU.
  __shared__ __align__(16) char smem[73728];
  ushort(*sA)[BM * BK] = reinterpret_cast<ushort(*)[BM * BK]>(smem);           // 3 x 8 KB
  ushort(*sB)[BN * BK] = reinterpret_cast<ushort(*)[BN * BK]>(smem + 24576);   // 3 x 16 KB

  int tid = threadIdx.x;
  int wave = tid >> 6, lane = tid & 63;

  // XCD N-partition: XCD x owns ntiles [8x, 8x+8); walk mtiles fastest so the
  // 2 MB W-panel stays L2-hot. 2048 % 8 == 0 -> bijective.
  int bid = blockIdx.x;
  int r2 = bid >> 3;                            // 0..255
  int ntile = (bid & 7) * 8 + (r2 >> 5);        // 0..63
  int mtile = r2 & 31;                          // 0..31
  int m0 = mtile * BM, n0 = ntile * BN;

  int wr = wave >> 2, wc = wave & 3;  // 2x4 wave grid; per-wave C: 64x64

  const ushort* gA = A + (size_t)m0 * D_K;
  const ushort* gB = W + (size_t)n0 * D_K;

  // staging: LDS slot (row, kg) <- global (row, kg ^ ((row>>1)&3)); linear LDS dest,
  // pre-swizzled per-lane global source (rule #21). ((128+row)>>1)&3 == ((row>>1)&3).
  int srow = tid >> 2;        // 0..127
  int kg = tid & 3;
  int ks = (kg ^ ((srow >> 1) & 3)) * 8;
  const ushort* srcA0 = gA + (size_t)srow * D_K + ks;                  // A rows 0..127
  const ushort* srcB0 = gB + (size_t)srow * D_K + ks;                  // B rows 0..127
  const ushort* srcB1 = gB + (size_t)(128 + srow) * D_K + ks;          // B rows 128..255
  int ldso = wave * 512;  // wave's 1KB chunk within an 8 KB half-region

#define STAGE(buf, kt) do {                              \
    GLOAD_LDS16(srcA0 + (kt), sA[buf] + ldso);           \
    GLOAD_LDS16(srcB0 + (kt), sB[buf] + ldso);           \
    GLOAD_LDS16(srcB1 + (kt), sB[buf] + 4096 + ldso);    \
  } while (0)

  // fragment read indices (swizzled): elem (r, kg0*8..+8) at r*32 + (kg0^((r>>1)&3))*8
  int kg0 = lane >> 4, l15 = lane & 15;
  int aIdx[4], bIdx[4];
#pragma unroll
  for (int m = 0; m < 4; ++m) {
    int r = wr * 64 + m * 16 + l15;
    aIdx[m] = r * 32 + ((kg0 ^ ((r >> 1) & 3)) << 3);
  }
#pragma unroll
  for (int n = 0; n < 4; ++n) {
    int r = wc * 64 + n * 16 + l15;
    bIdx[n] = r * 32 + ((kg0 ^ ((r >> 1) & 3)) << 3);
  }

  f32x4 acc[4][4] = {};

  STAGE(0, 0);
  STAGE(1, BK);

#pragma unroll
  for (int t = 0; t < NT; ++t) {
    // loop top: tile t's 3 loads are the wave's oldest; tile t+1's 3 stay in flight.
    if (t < NT - 1) { WAIT_BAR(3); } else { WAIT_BAR(0); }

    const ushort* sa = sA[t % 3];
    const ushort* sb = sB[t % 3];
    bf16x8 af[4], bf[4];
#pragma unroll
    for (int n = 0; n < 4; ++n) bf[n] = *reinterpret_cast<const bf16x8*>(&sb[bIdx[n]]);
#pragma unroll
    for (int m = 0; m < 4; ++m) af[m] = *reinterpret_cast<const bf16x8*>(&sa[aIdx[m]]);
    if (t + 2 < NT) STAGE((t + 2) % 3, (t + 2) * BK);  // buf (t+2)%3==(t-1)%3: reads retired

    __builtin_amdgcn_s_setprio(1);
#pragma unroll
    for (int m = 0; m < 4; ++m)
#pragma unroll
      for (int n = 0; n < 4; ++n)
        acc[m][n] = __builtin_amdgcn_mfma_f32_16x16x32_bf16(af[m], bf[n], acc[m][n], 0, 0, 0);
    __builtin_amdgcn_s_setprio(0);
    // closing barrier is next iteration's WAIT_BAR (or loop exit)
  }
#undef STAGE

  __syncthreads();  // all tile LDS reads retired; smem now reusable as sC

  // ---- LDS-transposed epilogue: full-line C stores ----
  // acc[m][n][r] = C-tile (row wr*64+m*16+lr*4+r, col wc*64+n*16+l15).
  // Per m-chunk: mask+bias -> sC[32][SCP] -> each wave stores 4 rows of 1 KB
  // contiguous (full 128B lines -> no L2 write-allocate fills).
  float* sC = reinterpret_cast<float*>(smem);  // 32*SCP*4 = 33.8 KB
  int lr = lane >> 4;
  float bj[4], rm[4];
#pragma unroll
  for (int n = 0; n < 4; ++n) {
    int col = n0 + wc * 64 + n * 16 + l15;
    bj[n] = bias[col];
    rm[n] = cmask[assign[col]];
  }
#pragma unroll
  for (int m = 0; m < 4; ++m) {
    float4 qm = *reinterpret_cast<const float4*>(&qmask[m0 + wr * 64 + m * 16 + lr * 4]);
    int rl = wr * 16 + lr * 4;  // local row in sC (strip wr, row-in-strip lr*4+r)
#pragma unroll
    for (int n = 0; n < 4; ++n) {
      int cc = wc * 64 + n * 16 + l15;
      sC[(rl + 0) * SCP + cc] = (acc[m][n][0] + bj[n]) * qm.x * rm[n];
      sC[(rl + 1) * SCP + cc] = (acc[m][n][1] + bj[n]) * qm.y * rm[n];
      sC[(rl + 2) * SCP + cc] = (acc[m][n][2] + bj[n]) * qm.z * rm[n];
      sC[(rl + 3) * SCP + cc] = (acc[m][n][3] + bj[n]) * qm.w * rm[n];
    }
    __syncthreads();
#pragma unroll
    for (int i = 0; i < 4; ++i) {
      int rr = wave * 4 + i;  // 0..31
      f32x4 v = *reinterpret_cast<const f32x4*>(&sC[rr * SCP + lane * 4]);
      int grow = m0 + ((rr >> 4) * 64) + m * 16 + (rr & 15);
      __builtin_nontemporal_store(
          v, reinterpret_cast<f32x4*>(&C[(size_t)grow * D_OUT + n0 + lane * 4]));
    }
    __syncthreads();  // readers done before next chunk overwrites sC
  }
}

extern "C" void kernel_launch(void* const* d_in, const int* in_sizes, int n_in,
                              void* d_out, int out_size, void* d_ws, size_t ws_size,
                              hipStream_t stream) {
  const float* input     = (const float*)d_in[0];
  const float* weight    = (const float*)d_in[1];
  const float* bias      = (const float*)d_in[2];
  const float* centroids = (const float*)d_in[3];
  const int*   assign    = (const int*)d_in[4];
  float* out = (float*)d_out;

  // ws layout (bytes):
  //   A_bf16 : 0          (4 MiB)
  //   W_bf16 : 4,194,304  (16 MiB)
  //   qmask  : 20,971,520 (16 KB)
  //   cmask  : 20,987,904 (1 KB)
  //   centT4 : 21,000,192 (512 KB)
  char* ws = (char*)d_ws;
  ushort* A_bf   = (ushort*)ws;
  ushort* W_bf   = (ushort*)(ws + 4194304);
  float*  qmask  = (float*)(ws + 20971520);
  float*  cmask  = (float*)(ws + 20987904);
  float4* centT4 = (float4*)(ws + 21000192);

  cvt_bf16_kernel<<<(D_OUT * D_K / 8 + 255) / 256, 256, 0, stream>>>(weight, W_bf, D_OUT * D_K / 8);
  transpose_cent_kernel<<<128, 256, 0, stream>>>(centroids, centT4, cmask);
  routing_kernel<<<N_Q / 8, 256, 0, stream>>>(input, centT4, qmask, cmask, A_bf);
  gemm_masked_kernel<<<(N_Q / BM) * (D_OUT / BN), 512, 0, stream>>>(
      A_bf, W_bf, bias, assign, qmask, cmask, out);
}